// Round 2
// baseline (20163.773 us; speedup 1.0000x reference)
//
#include <hip/hip_runtime.h>
#include <hip/hip_bf16.h>

// ---------------------------------------------------------------------------
// BiLSTM (persistent bf16-MFMA kernel, register-resident weights + cell state)
// + CRF forward.  Sizes fixed by the problem:
constexpr int B_ = 64, S_ = 512, E_ = 300, H_ = 512, T_ = 12;
constexpr int G4 = 4 * H_;          // 2048 gate rows
constexpr int KPADX = 320;          // E padded to 320 (zeros 300..319)
constexpr int KTOT = KPADX + H_;    // 832 total K (x | h)
constexpr int KC_TOT = KTOT / 32;   // 26 MFMA k-chunks
constexpr int NT16 = G4 / 16;       // 128 16-wide n tiles
constexpr float NEGV = -10000.0f;
constexpr int BPD = 128;            // blocks per direction (32 nt x 4 mt)
constexpr int ASTR = 840;           // LDS A-row stride in shorts (832 + 8)

typedef __attribute__((ext_vector_type(8))) short bf16x8_t;
typedef __attribute__((ext_vector_type(4))) float f32x4_t;

// ---- workspace layout (bytes) ---------------------------------------------
constexpr size_t WC_OFF = 0;
constexpr size_t WC_BYTES = (size_t)2 * NT16 * KC_TOT * 64 * 8 * 2;  // 6,815,744
constexpr size_t XC_OFF = WC_OFF + WC_BYTES;
constexpr size_t XC_BYTES = (size_t)S_ * B_ * KPADX * 2;             // 20,971,520
constexpr size_t HH_OFF = XC_OFF + XC_BYTES;
constexpr size_t HH_BYTES = (size_t)2 * (S_ + 1) * B_ * H_ * 2;      // 67,239,936
constexpr size_t FE_OFF = HH_OFF + HH_BYTES;
constexpr size_t FE_BYTES = (size_t)S_ * B_ * T_ * 4;                // 1,572,864
constexpr size_t LSE_OFF = FE_OFF + FE_BYTES;
constexpr size_t BAR_OFF = LSE_OFF + 256;   // int bar[128]: bar[0]=dir0, bar[64]=dir1

// ---------------------------------------------------------------------------
// prep: (1) combined weights -> bf16 MFMA B-fragment order (unchanged from
// round 0); (2) h0 -> bf16 h_hist slot 0; (3) embedding gather: xc[s][b][320]
// bf16 (zeros past E); (4) zero barrier counters.
__global__ void prep_kernel(const float* __restrict__ Wih_f, const float* __restrict__ Whh_f,
                            const float* __restrict__ Wih_b, const float* __restrict__ Whh_b,
                            const float* __restrict__ h0,
                            const int* __restrict__ tokens, const float* __restrict__ Wemb,
                            char* __restrict__ ws) {
  __hip_bfloat16* wc = (__hip_bfloat16*)(ws + WC_OFF);
  __hip_bfloat16* xc = (__hip_bfloat16*)(ws + XC_OFF);
  __hip_bfloat16* hh = (__hip_bfloat16*)(ws + HH_OFF);
  int* bar = (int*)(ws + BAR_OFF);
  const int WCN = 2 * NT16 * KC_TOT * 64;   // 425,984
  const int H0N = 2 * B_ * H_;              // 65,536
  const int XCN = S_ * B_ * (KPADX / 8);    // 1,310,720
  int idx = blockIdx.x * 256 + threadIdx.x;
  if (idx < WCN) {
    int lane = idx & 63;
    int r = idx >> 6;
    int kc = r % KC_TOT; r /= KC_TOT;
    int tt = r % NT16;
    int dir = r / NT16;
    int n16 = lane & 15, quad = lane >> 4;
    int nt = tt >> 2, gate = tt & 3;
    int j = gate * H_ + nt * 16 + n16;   // original gate row
    int k0 = kc * 32 + quad * 8;
    const float* Wih = dir ? Wih_b : Wih_f;
    const float* Whh = dir ? Whh_b : Whh_f;
    __hip_bfloat16* dst = wc + (size_t)idx * 8;
    #pragma unroll
    for (int jj = 0; jj < 8; jj++) {
      int k = k0 + jj;
      float f;
      if (k < E_) f = Wih[(size_t)j * E_ + k];
      else if (k < KPADX) f = 0.f;
      else f = Whh[(size_t)j * H_ + (k - KPADX)];
      dst[jj] = __float2bfloat16(f);
    }
  } else if (idx < WCN + H0N) {
    int i = idx - WCN;                       // dir*B*H + b*H + h
    int dir = i / (B_ * H_), rem = i % (B_ * H_);
    hh[(size_t)dir * (S_ + 1) * B_ * H_ + rem] = __float2bfloat16(h0[i]);
  } else if (idx < WCN + H0N + XCN) {
    int i = idx - WCN - H0N;                 // sb*40 + c8
    int c8 = i % 40, sb = i / 40;            // sb = s*B + b
    int s = sb >> 6, b = sb & 63;
    int k0 = c8 * 8;
    const float* src = Wemb + (size_t)tokens[(size_t)b * S_ + s] * E_;
    __hip_bfloat16 v[8];
    if (k0 + 8 <= E_) {
      float4 f0 = *(const float4*)(src + k0);
      float4 f1 = *(const float4*)(src + k0 + 4);
      v[0] = __float2bfloat16(f0.x); v[1] = __float2bfloat16(f0.y);
      v[2] = __float2bfloat16(f0.z); v[3] = __float2bfloat16(f0.w);
      v[4] = __float2bfloat16(f1.x); v[5] = __float2bfloat16(f1.y);
      v[6] = __float2bfloat16(f1.z); v[7] = __float2bfloat16(f1.w);
    } else {
      #pragma unroll
      for (int jj = 0; jj < 8; jj++) {
        int k = k0 + jj;
        v[jj] = __float2bfloat16(k < E_ ? src[k] : 0.f);
      }
    }
    *(uint4*)(xc + (size_t)sb * KPADX + k0) = *(const uint4*)v;
  } else if (idx == WCN + H0N + XCN) {
    bar[0] = 0;
  } else if (idx == WCN + H0N + XCN + 1) {
    bar[64] = 0;
  }
}

// ---------------------------------------------------------------------------
// Persistent BiLSTM. grid = 256 blocks = dir(2) x nt(32) x mt(4), block = 256.
// Block (dir,nt,mt): batches [mt*16, mt*16+16), h-range [nt*16, nt*16+16),
// all 4 gates (wave = gate). Weights in registers (26 frags/wave), cell state
// in a register (1 (b,h) pair per thread). Per-dir atomic barrier each step
// with device-scope fences (cross-XCD h visibility).
__launch_bounds__(256, 1)
__global__ void lstm_persist(const float* __restrict__ bias_f,
                             const float* __restrict__ bias_b,
                             const float* __restrict__ c0,
                             char* __restrict__ ws) {
  __shared__ short pool[16 * ASTR];      // 26,880 B A-tile
  __shared__ float gl[4 * 16 * 17];      // 4,352 B gate exchange
  const int bid = blockIdx.x;
  const int dir = bid >> 7, rr_ = bid & 127, nt = rr_ >> 2, mt = rr_ & 3;
  const int tid = threadIdx.x, lane = tid & 63, wv = tid >> 6;
  const int quad = lane >> 4, l16 = lane & 15;
  const __hip_bfloat16* wc = (const __hip_bfloat16*)(ws + WC_OFF);
  const __hip_bfloat16* xc = (const __hip_bfloat16*)(ws + XC_OFF);
  __hip_bfloat16* hh = (__hip_bfloat16*)(ws + HH_OFF);
  int* bar = (int*)(ws + BAR_OFF) + dir * 64;

  // --- load B fragments into registers, once ---
  bf16x8_t bfr[KC_TOT];
  #pragma unroll
  for (int kc = 0; kc < KC_TOT; kc++) {
    size_t boff = (((size_t)dir * NT16 + (nt * 4 + wv)) * KC_TOT + kc) * 64 + lane;
    bfr[kc] = *(const bf16x8_t*)(wc + boff * 8);
  }
  // --- per-thread cell state + biases ---
  const int bo = tid >> 4, hl = tid & 15;       // batch-offset, h-offset
  const int b = mt * 16 + bo, hg = nt * 16 + hl;
  float c = c0[(size_t)(dir * B_ + b) * H_ + hg];
  const float* bias = dir ? bias_b : bias_f;
  const float bi_i = bias[0 * H_ + hg], bi_f = bias[1 * H_ + hg];
  const float bi_g = bias[2 * H_ + hg], bi_o = bias[3 * H_ + hg];

  for (int s = 0; s < S_; s++) {
    const int spos = dir ? (S_ - 1 - s) : s;
    // --- stage A-tile: 16 rows x 104 uint4 chunks (x | h_prev), bf16 ---
    const __hip_bfloat16* hrow = hh + (size_t)(dir * (S_ + 1) + s) * B_ * H_;
    for (int i = tid; i < 16 * 104; i += 256) {
      int row = i / 104, c8 = i % 104;
      uint4 val;
      if (c8 < 40) {
        val = *(const uint4*)(xc + ((size_t)spos * B_ + mt * 16 + row) * KPADX + c8 * 8);
      } else {
        val = *(const uint4*)(hrow + (size_t)(mt * 16 + row) * H_ + (c8 - 40) * 8);
      }
      *(uint4*)(pool + row * ASTR + c8 * 8) = val;
    }
    __syncthreads();
    // --- MFMA K-loop: 26 chunks, B from registers ---
    f32x4_t acc = (f32x4_t)(0.f);
    #pragma unroll
    for (int kc = 0; kc < KC_TOT; kc++) {
      bf16x8_t af = *(const bf16x8_t*)(pool + l16 * ASTR + kc * 32 + quad * 8);
      acc = __builtin_amdgcn_mfma_f32_16x16x32_bf16(af, bfr[kc], acc, 0, 0, 0);
    }
    __syncthreads();   // A-reads done (pool reusable), prev gl consumed
    // --- gate exchange: C/D row = quad*4+r = batch-offset, col = l16 = hl ---
    #pragma unroll
    for (int r = 0; r < 4; r++)
      gl[(wv * 16 + quad * 4 + r) * 17 + l16] = acc[r];
    __syncthreads();
    // --- elementwise cell update (c in register) ---
    float gi = gl[(0 * 16 + bo) * 17 + hl] + bi_i;
    float gf = gl[(1 * 16 + bo) * 17 + hl] + bi_f;
    float gg = gl[(2 * 16 + bo) * 17 + hl] + bi_g;
    float go = gl[(3 * 16 + bo) * 17 + hl] + bi_o;
    float ii = 1.f / (1.f + __expf(-gi));
    float ff = 1.f / (1.f + __expf(-gf));
    float gt = 1.f - 2.f / (1.f + __expf(2.f * gg));   // tanh
    float oo = 1.f / (1.f + __expf(-go));
    c = ff * c + ii * gt;
    float hv = oo * (1.f - 2.f / (1.f + __expf(2.f * c)));
    hh[((size_t)(dir * (S_ + 1) + s + 1) * B_ + b) * H_ + hg] = __float2bfloat16(hv);
    // --- cross-block barrier (per direction) with device-scope fences ---
    if (s < S_ - 1) {
      __threadfence();          // release: push h stores past L2 (cross-XCD)
      __syncthreads();
      if (tid == 0) {
        __hip_atomic_fetch_add(bar, 1, __ATOMIC_RELEASE, __HIP_MEMORY_SCOPE_AGENT);
        int target = (s + 1) * BPD;
        while (__hip_atomic_load(bar, __ATOMIC_RELAXED, __HIP_MEMORY_SCOPE_AGENT) < target)
          __builtin_amdgcn_s_sleep(2);
      }
      __syncthreads();
      __threadfence();          // acquire: invalidate stale cached lines
    }
  }
}

// ---------------------------------------------------------------------------
// feats[s,b,t] = [hf(s) | hb(s)] . W_out[t,:] + b_out[t].  block per s.
__launch_bounds__(256)
__global__ void feats_kernel(const float* __restrict__ Wout,
                             const float* __restrict__ bout,
                             char* __restrict__ ws) {
  __shared__ float wl[12 * 1024];   // 48 KB
  const int s = blockIdx.x, tid = threadIdx.x;
  for (int i = tid; i < 12 * 1024 / 4; i += 256)
    *(float4*)(wl + i * 4) = *(const float4*)(Wout + i * 4);
  __syncthreads();
  const __hip_bfloat16* hh = (const __hip_bfloat16*)(ws + HH_OFF);
  float* fe = (float*)(ws + FE_OFF);
  int b = tid >> 2, tg = tid & 3, t0 = tg * 3;
  const __hip_bfloat16* hf = hh + (size_t)(0 * (S_ + 1) + s + 1) * B_ * H_ + (size_t)b * H_;
  const __hip_bfloat16* hb = hh + (size_t)(1 * (S_ + 1) + (S_ - s)) * B_ * H_ + (size_t)b * H_;
  float a0 = 0.f, a1 = 0.f, a2 = 0.f;
  for (int half = 0; half < 2; half++) {
    const __hip_bfloat16* hp = half ? hb : hf;
    int wof = half * 512;
    for (int k = 0; k < 512; k += 8) {
      uint4 raw = *(const uint4*)(hp + k);
      const __hip_bfloat16* hv = (const __hip_bfloat16*)&raw;
      float hfl[8];
      #pragma unroll
      for (int j = 0; j < 8; j++) hfl[j] = __bfloat162float(hv[j]);
      #pragma unroll
      for (int j = 0; j < 8; j++) {
        a0 += hfl[j] * wl[(t0 + 0) * 1024 + wof + k + j];
        a1 += hfl[j] * wl[(t0 + 1) * 1024 + wof + k + j];
        a2 += hfl[j] * wl[(t0 + 2) * 1024 + wof + k + j];
      }
    }
  }
  float* o = fe + ((size_t)s * B_ + b) * T_;
  o[t0 + 0] = a0 + bout[t0 + 0];
  o[t0 + 1] = a1 + bout[t0 + 1];
  o[t0 + 2] = a2 + bout[t0 + 2];
}

// ---------------------------------------------------------------------------
// CRF forward scan: one wave per batch element; lane = next-tag (<12).
__launch_bounds__(64)
__global__ void crf_kernel(const int* __restrict__ lengths,
                           const float* __restrict__ trans,
                           char* __restrict__ ws) {
  const int b = blockIdx.x, lane = threadIdx.x;
  const float* fe = (const float*)(ws + FE_OFF);
  float* lse = (float*)(ws + LSE_OFF);
  float tr[12];
  #pragma unroll
  for (int p = 0; p < 12; p++) tr[p] = (lane < 12) ? trans[lane * 12 + p] : 0.f;
  float tstop = (lane < 12) ? trans[11 * 12 + lane] : 0.f;  // STOP row
  float alpha = (lane == 10) ? 0.f : NEGV;                  // START tag
  const int len = lengths[b];
  for (int s = 0; s < S_; s++) {
    float feat = (lane < 12) ? fe[((size_t)s * B_ + b) * T_ + lane] : 0.f;
    float av[12];
    #pragma unroll
    for (int p = 0; p < 12; p++) av[p] = __shfl(alpha, p, 64) + tr[p];
    float mx = av[0];
    #pragma unroll
    for (int p = 1; p < 12; p++) mx = fmaxf(mx, av[p]);
    float sum = 0.f;
    #pragma unroll
    for (int p = 0; p < 12; p++) sum += __expf(av[p] - mx);
    float nw = mx + __logf(sum) + feat;
    if (s < len && lane < 12) alpha = nw;
  }
  float tv = (lane < 12) ? (alpha + tstop) : -3.0e38f;
  float mx = tv;
  #pragma unroll
  for (int off = 32; off > 0; off >>= 1) mx = fmaxf(mx, __shfl_xor(mx, off, 64));
  float sum = __expf(tv - mx);
  #pragma unroll
  for (int off = 32; off > 0; off >>= 1) sum += __shfl_xor(sum, off, 64);
  if (lane == 0) lse[b] = mx + __logf(sum);
}

__global__ void final_kernel(char* __restrict__ ws, float* __restrict__ out) {
  const float* lse = (const float*)(ws + LSE_OFF);
  float v = lse[threadIdx.x];
  #pragma unroll
  for (int off = 32; off > 0; off >>= 1) v += __shfl_xor(v, off, 64);
  if (threadIdx.x == 0) out[0] = v * (1.f / 64.f);
}

// ---------------------------------------------------------------------------
extern "C" void kernel_launch(void* const* d_in, const int* in_sizes, int n_in,
                              void* d_out, int out_size, void* d_ws, size_t ws_size,
                              hipStream_t stream) {
  (void)in_sizes; (void)n_in; (void)out_size; (void)ws_size;
  const int* tokens = (const int*)d_in[0];
  const int* lengths = (const int*)d_in[1];
  const float* Wemb = (const float*)d_in[2];
  const float* Wih_f = (const float*)d_in[3];
  const float* Whh_f = (const float*)d_in[4];
  const float* b_f = (const float*)d_in[5];
  const float* Wih_b = (const float*)d_in[6];
  const float* Whh_b = (const float*)d_in[7];
  const float* b_b = (const float*)d_in[8];
  const float* h0 = (const float*)d_in[9];
  const float* c0 = (const float*)d_in[10];
  const float* Wout = (const float*)d_in[11];
  const float* bout = (const float*)d_in[12];
  const float* trans = (const float*)d_in[13];
  char* ws = (char*)d_ws;
  float* out = (float*)d_out;

  int prep_items = 2 * NT16 * KC_TOT * 64 + 2 * B_ * H_ + S_ * B_ * (KPADX / 8) + 2;
  hipLaunchKernelGGL(prep_kernel, dim3((prep_items + 255) / 256), dim3(256), 0, stream,
                     Wih_f, Whh_f, Wih_b, Whh_b, h0, tokens, Wemb, ws);
  hipLaunchKernelGGL(lstm_persist, dim3(256), dim3(256), 0, stream, b_f, b_b, c0, ws);
  hipLaunchKernelGGL(feats_kernel, dim3(S_), dim3(256), 0, stream, Wout, bout, ws);
  hipLaunchKernelGGL(crf_kernel, dim3(B_), dim3(64), 0, stream, lengths, trans, ws);
  hipLaunchKernelGGL(final_kernel, dim3(1), dim3(64), 0, stream, ws, out);
}

// Round 3
// 4157.336 us; speedup vs baseline: 4.8502x; 4.8502x over previous
//
#include <hip/hip_runtime.h>
#include <hip/hip_bf16.h>

// ---------------------------------------------------------------------------
// BiLSTM (persistent bf16-MFMA kernel, register-resident weights + cell state,
// FENCE-FREE cross-XCD coherence via sc1 relaxed atomics) + CRF forward.
constexpr int B_ = 64, S_ = 512, E_ = 300, H_ = 512, T_ = 12;
constexpr int G4 = 4 * H_;          // 2048 gate rows
constexpr int KPADX = 320;          // E padded to 320 (zeros 300..319)
constexpr int KTOT = KPADX + H_;    // 832 total K (x | h)
constexpr int KC_TOT = KTOT / 32;   // 26 MFMA k-chunks
constexpr int NT16 = G4 / 16;       // 128 16-wide n tiles
constexpr float NEGV = -10000.0f;
constexpr int ASTR = 840;           // LDS A-row stride in shorts (832 + 8)

typedef __attribute__((ext_vector_type(8))) short bf16x8_t;
typedef __attribute__((ext_vector_type(4))) float f32x4_t;

// ---- workspace layout (bytes) ---------------------------------------------
constexpr size_t WC_OFF = 0;
constexpr size_t WC_BYTES = (size_t)2 * NT16 * KC_TOT * 64 * 8 * 2;  // 6,815,744
constexpr size_t XC_OFF = WC_OFF + WC_BYTES;
constexpr size_t XC_BYTES = (size_t)S_ * B_ * KPADX * 2;             // 20,971,520
constexpr size_t HH_OFF = XC_OFF + XC_BYTES;
constexpr size_t HH_BYTES = (size_t)2 * (S_ + 1) * B_ * H_ * 2;      // 67,239,936
constexpr size_t FE_OFF = HH_OFF + HH_BYTES;
constexpr size_t FE_BYTES = (size_t)S_ * B_ * T_ * 4;                // 1,572,864
constexpr size_t LSE_OFF = FE_OFF + FE_BYTES;
constexpr size_t BAR_OFF = LSE_OFF + 256;
// bar layout (ints): counter(dir,g) at (dir*8+g)*32  (128B apart), 1024 zeroed

// ---------------------------------------------------------------------------
// prep: (1) weights -> bf16 MFMA B-fragment order; (2) h0 -> bf16 h_hist slot
// 0; (3) embedding gather xc[s][b][320] bf16; (4) zero barrier region.
__global__ void prep_kernel(const float* __restrict__ Wih_f, const float* __restrict__ Whh_f,
                            const float* __restrict__ Wih_b, const float* __restrict__ Whh_b,
                            const float* __restrict__ h0,
                            const int* __restrict__ tokens, const float* __restrict__ Wemb,
                            char* __restrict__ ws) {
  __hip_bfloat16* wc = (__hip_bfloat16*)(ws + WC_OFF);
  __hip_bfloat16* xc = (__hip_bfloat16*)(ws + XC_OFF);
  __hip_bfloat16* hh = (__hip_bfloat16*)(ws + HH_OFF);
  int* bar = (int*)(ws + BAR_OFF);
  const int WCN = 2 * NT16 * KC_TOT * 64;   // 425,984
  const int H0N = 2 * B_ * H_;              // 65,536
  const int XCN = S_ * B_ * (KPADX / 8);    // 1,310,720
  int idx = blockIdx.x * 256 + threadIdx.x;
  if (idx < WCN) {
    int lane = idx & 63;
    int r = idx >> 6;
    int kc = r % KC_TOT; r /= KC_TOT;
    int tt = r % NT16;
    int dir = r / NT16;
    int n16 = lane & 15, quad = lane >> 4;
    int nt = tt >> 2, gate = tt & 3;
    int j = gate * H_ + nt * 16 + n16;   // original gate row
    int k0 = kc * 32 + quad * 8;
    const float* Wih = dir ? Wih_b : Wih_f;
    const float* Whh = dir ? Whh_b : Whh_f;
    __hip_bfloat16* dst = wc + (size_t)idx * 8;
    #pragma unroll
    for (int jj = 0; jj < 8; jj++) {
      int k = k0 + jj;
      float f;
      if (k < E_) f = Wih[(size_t)j * E_ + k];
      else if (k < KPADX) f = 0.f;
      else f = Whh[(size_t)j * H_ + (k - KPADX)];
      dst[jj] = __float2bfloat16(f);
    }
  } else if (idx < WCN + H0N) {
    int i = idx - WCN;                       // dir*B*H + b*H + h
    int dir = i / (B_ * H_), rem = i % (B_ * H_);
    hh[(size_t)dir * (S_ + 1) * B_ * H_ + rem] = __float2bfloat16(h0[i]);
  } else if (idx < WCN + H0N + XCN) {
    int i = idx - WCN - H0N;                 // sb*40 + c8
    int c8 = i % 40, sb = i / 40;            // sb = s*B + b
    int s = sb >> 6, b = sb & 63;
    int k0 = c8 * 8;
    const float* src = Wemb + (size_t)tokens[(size_t)b * S_ + s] * E_;
    __hip_bfloat16 v[8];
    if (k0 + 8 <= E_) {
      float4 f0 = *(const float4*)(src + k0);
      float4 f1 = *(const float4*)(src + k0 + 4);
      v[0] = __float2bfloat16(f0.x); v[1] = __float2bfloat16(f0.y);
      v[2] = __float2bfloat16(f0.z); v[3] = __float2bfloat16(f0.w);
      v[4] = __float2bfloat16(f1.x); v[5] = __float2bfloat16(f1.y);
      v[6] = __float2bfloat16(f1.z); v[7] = __float2bfloat16(f1.w);
    } else {
      #pragma unroll
      for (int jj = 0; jj < 8; jj++) {
        int k = k0 + jj;
        v[jj] = __float2bfloat16(k < E_ ? src[k] : 0.f);
      }
    }
    *(uint4*)(xc + (size_t)sb * KPADX + k0) = *(const uint4*)v;
  } else if (idx < WCN + H0N + XCN + 1024) {
    bar[idx - WCN - H0N - XCN] = 0;
  }
}

// ---------------------------------------------------------------------------
// Persistent BiLSTM. grid = 256 = dir(2) x nt(32) x mt(4), block = 256.
// Weights in registers; cell state in a register. Cross-XCD h exchange via
// sc1 (agent-scope relaxed) stores/loads — NO fences (no wbl2/inv) anywhere.
// Barrier: 8 padded group counters per dir (16 arrivals each), every block's
// wave 0 polls all 8 in parallel (lanes 0..7 + __all).
__launch_bounds__(256, 1)
__global__ void lstm_persist(const float* __restrict__ bias_f,
                             const float* __restrict__ bias_b,
                             const float* __restrict__ c0,
                             char* __restrict__ ws) {
  __shared__ short pool[16 * ASTR];      // 26,880 B A-tile
  __shared__ float gl[4 * 16 * 17];      // 4,352 B gate exchange
  const int bid = blockIdx.x;
  const int dir = bid >> 7, rr_ = bid & 127, nt = rr_ >> 2, mt = rr_ & 3;
  const int tid = threadIdx.x, lane = tid & 63, wv = tid >> 6;
  const int quad = lane >> 4, l16 = lane & 15;
  const __hip_bfloat16* wc = (const __hip_bfloat16*)(ws + WC_OFF);
  const __hip_bfloat16* xc = (const __hip_bfloat16*)(ws + XC_OFF);
  unsigned* hh_u = (unsigned*)(ws + HH_OFF);
  int* bar = (int*)(ws + BAR_OFF);
  int* mycnt = &bar[(dir * 8 + (rr_ & 7)) * 32];

  // --- load B fragments into registers, once ---
  bf16x8_t bfr[KC_TOT];
  #pragma unroll
  for (int kc = 0; kc < KC_TOT; kc++) {
    size_t boff = (((size_t)dir * NT16 + (nt * 4 + wv)) * KC_TOT + kc) * 64 + lane;
    bfr[kc] = *(const bf16x8_t*)(wc + boff * 8);
  }
  // --- per-thread cell state + biases ---
  const int bo = tid >> 4, hl = tid & 15;       // batch-offset, h-offset
  const int b = mt * 16 + bo, hg = nt * 16 + hl;
  float c = c0[(size_t)(dir * B_ + b) * H_ + hg];
  const float* bias = dir ? bias_b : bias_f;
  const float bi_i = bias[0 * H_ + hg], bi_f = bias[1 * H_ + hg];
  const float bi_g = bias[2 * H_ + hg], bi_o = bias[3 * H_ + hg];

  // --- pre-stage x(0) into pool x-region (cached loads; xc never stale) ---
  {
    int spos0 = dir ? (S_ - 1) : 0;
    for (int i = tid; i < 16 * 40; i += 256) {
      int row = i / 40, c8 = i % 40;
      *(uint4*)(pool + row * ASTR + c8 * 8) =
          *(const uint4*)(xc + ((size_t)spos0 * B_ + mt * 16 + row) * KPADX + c8 * 8);
    }
  }

  for (int s = 0; s < S_; s++) {
    // --- stage h(s): sc1 loads (bypass possibly-stale per-XCD L2) ---
    const size_t hbase_u = ((size_t)(dir * (S_ + 1) + s) * B_ + mt * 16) * (H_ / 2);
    #pragma unroll
    for (int k = 0; k < 16; k++) {
      int i = tid + k * 256;
      int row = i >> 8, uc = i & 255;
      unsigned v = __hip_atomic_load(hh_u + hbase_u + (row << 8) + uc,
                                     __ATOMIC_RELAXED, __HIP_MEMORY_SCOPE_AGENT);
      *(unsigned*)(pool + row * ASTR + KPADX + uc * 2) = v;
    }
    __syncthreads();
    // --- MFMA K-loop: 26 chunks, B from registers ---
    f32x4_t acc = (f32x4_t)(0.f);
    #pragma unroll
    for (int kc = 0; kc < KC_TOT; kc++) {
      bf16x8_t af = *(const bf16x8_t*)(pool + l16 * ASTR + kc * 32 + quad * 8);
      acc = __builtin_amdgcn_mfma_f32_16x16x32_bf16(af, bfr[kc], acc, 0, 0, 0);
    }
    __syncthreads();   // pool A-reads done
    // --- gate exchange: C/D row = quad*4+r = batch-offset, col = l16 = hl ---
    #pragma unroll
    for (int r = 0; r < 4; r++)
      gl[(wv * 16 + quad * 4 + r) * 17 + l16] = acc[r];
    // --- overlap: prefetch x(s+1) into pool x-region (barrier-independent) ---
    if (s + 1 < S_) {
      int sposn = dir ? (S_ - 2 - s) : (s + 1);
      for (int i = tid; i < 16 * 40; i += 256) {
        int row = i / 40, c8 = i % 40;
        *(uint4*)(pool + row * ASTR + c8 * 8) =
            *(const uint4*)(xc + ((size_t)sposn * B_ + mt * 16 + row) * KPADX + c8 * 8);
      }
    }
    __syncthreads();
    // --- elementwise cell update (c in register) ---
    float gi = gl[(0 * 16 + bo) * 17 + hl] + bi_i;
    float gf = gl[(1 * 16 + bo) * 17 + hl] + bi_f;
    float gg = gl[(2 * 16 + bo) * 17 + hl] + bi_g;
    float go = gl[(3 * 16 + bo) * 17 + hl] + bi_o;
    float ii = 1.f / (1.f + __expf(-gi));
    float ff = 1.f / (1.f + __expf(-gf));
    float gt = 1.f - 2.f / (1.f + __expf(2.f * gg));   // tanh
    float oo = 1.f / (1.f + __expf(-go));
    c = ff * c + ii * gt;
    float hv = oo * (1.f - 2.f / (1.f + __expf(2.f * c)));
    // --- h store: pack 2 bf16 -> one sc1 (write-through) dword store ---
    float hn = __shfl_xor(hv, 1, 64);    // partner shares (bo, hl^1)
    if ((hl & 1) == 0) {
      unsigned short ulo = __builtin_bit_cast(unsigned short, __float2bfloat16(hv));
      unsigned short uhi = __builtin_bit_cast(unsigned short, __float2bfloat16(hn));
      unsigned pk = ((unsigned)uhi << 16) | (unsigned)ulo;
      size_t uidx = (((size_t)(dir * (S_ + 1) + s + 1) * B_ + b) * H_ + hg) >> 1;
      __hip_atomic_store(hh_u + uidx, pk, __ATOMIC_RELAXED, __HIP_MEMORY_SCOPE_AGENT);
    }
    // --- fence-free cross-block barrier (per direction) ---
    if (s < S_ - 1) {
      asm volatile("s_waitcnt vmcnt(0)" ::: "memory");  // h stores at LLC
      __syncthreads();                                   // all waves drained
      if (wv == 0) {
        if (lane == 0)
          __hip_atomic_fetch_add(mycnt, 1, __ATOMIC_RELAXED, __HIP_MEMORY_SCOPE_AGENT);
        const int target = 16 * (s + 1);
        for (;;) {
          int v = (lane < 8)
              ? __hip_atomic_load(&bar[(dir * 8 + lane) * 32],
                                  __ATOMIC_RELAXED, __HIP_MEMORY_SCOPE_AGENT)
              : target;
          if (__all(v >= target)) break;
          __builtin_amdgcn_s_sleep(2);
        }
      }
      __syncthreads();
    }
  }
}

// ---------------------------------------------------------------------------
// feats[s,b,t] = [hf(s) | hb(s)] . W_out[t,:] + b_out[t].  block per s.
__launch_bounds__(256)
__global__ void feats_kernel(const float* __restrict__ Wout,
                             const float* __restrict__ bout,
                             char* __restrict__ ws) {
  __shared__ float wl[12 * 1024];   // 48 KB
  const int s = blockIdx.x, tid = threadIdx.x;
  for (int i = tid; i < 12 * 1024 / 4; i += 256)
    *(float4*)(wl + i * 4) = *(const float4*)(Wout + i * 4);
  __syncthreads();
  const __hip_bfloat16* hh = (const __hip_bfloat16*)(ws + HH_OFF);
  float* fe = (float*)(ws + FE_OFF);
  int b = tid >> 2, tg = tid & 3, t0 = tg * 3;
  const __hip_bfloat16* hf = hh + (size_t)(0 * (S_ + 1) + s + 1) * B_ * H_ + (size_t)b * H_;
  const __hip_bfloat16* hb = hh + (size_t)(1 * (S_ + 1) + (S_ - s)) * B_ * H_ + (size_t)b * H_;
  float a0 = 0.f, a1 = 0.f, a2 = 0.f;
  for (int half = 0; half < 2; half++) {
    const __hip_bfloat16* hp = half ? hb : hf;
    int wof = half * 512;
    for (int k = 0; k < 512; k += 8) {
      uint4 raw = *(const uint4*)(hp + k);
      const __hip_bfloat16* hv = (const __hip_bfloat16*)&raw;
      float hfl[8];
      #pragma unroll
      for (int j = 0; j < 8; j++) hfl[j] = __bfloat162float(hv[j]);
      #pragma unroll
      for (int j = 0; j < 8; j++) {
        a0 += hfl[j] * wl[(t0 + 0) * 1024 + wof + k + j];
        a1 += hfl[j] * wl[(t0 + 1) * 1024 + wof + k + j];
        a2 += hfl[j] * wl[(t0 + 2) * 1024 + wof + k + j];
      }
    }
  }
  float* o = fe + ((size_t)s * B_ + b) * T_;
  o[t0 + 0] = a0 + bout[t0 + 0];
  o[t0 + 1] = a1 + bout[t0 + 1];
  o[t0 + 2] = a2 + bout[t0 + 2];
}

// ---------------------------------------------------------------------------
// CRF forward scan: one wave per batch element; lane = next-tag (<12).
__launch_bounds__(64)
__global__ void crf_kernel(const int* __restrict__ lengths,
                           const float* __restrict__ trans,
                           char* __restrict__ ws) {
  const int b = blockIdx.x, lane = threadIdx.x;
  const float* fe = (const float*)(ws + FE_OFF);
  float* lse = (float*)(ws + LSE_OFF);
  float tr[12];
  #pragma unroll
  for (int p = 0; p < 12; p++) tr[p] = (lane < 12) ? trans[lane * 12 + p] : 0.f;
  float tstop = (lane < 12) ? trans[11 * 12 + lane] : 0.f;  // STOP row
  float alpha = (lane == 10) ? 0.f : NEGV;                  // START tag
  const int len = lengths[b];
  for (int s = 0; s < S_; s++) {
    float feat = (lane < 12) ? fe[((size_t)s * B_ + b) * T_ + lane] : 0.f;
    float av[12];
    #pragma unroll
    for (int p = 0; p < 12; p++) av[p] = __shfl(alpha, p, 64) + tr[p];
    float mx = av[0];
    #pragma unroll
    for (int p = 1; p < 12; p++) mx = fmaxf(mx, av[p]);
    float sum = 0.f;
    #pragma unroll
    for (int p = 0; p < 12; p++) sum += __expf(av[p] - mx);
    float nw = mx + __logf(sum) + feat;
    if (s < len && lane < 12) alpha = nw;
  }
  float tv = (lane < 12) ? (alpha + tstop) : -3.0e38f;
  float mx = tv;
  #pragma unroll
  for (int off = 32; off > 0; off >>= 1) mx = fmaxf(mx, __shfl_xor(mx, off, 64));
  float sum = __expf(tv - mx);
  #pragma unroll
  for (int off = 32; off > 0; off >>= 1) sum += __shfl_xor(sum, off, 64);
  if (lane == 0) lse[b] = mx + __logf(sum);
}

__global__ void final_kernel(char* __restrict__ ws, float* __restrict__ out) {
  const float* lse = (const float*)(ws + LSE_OFF);
  float v = lse[threadIdx.x];
  #pragma unroll
  for (int off = 32; off > 0; off >>= 1) v += __shfl_xor(v, off, 64);
  if (threadIdx.x == 0) out[0] = v * (1.f / 64.f);
}

// ---------------------------------------------------------------------------
extern "C" void kernel_launch(void* const* d_in, const int* in_sizes, int n_in,
                              void* d_out, int out_size, void* d_ws, size_t ws_size,
                              hipStream_t stream) {
  (void)in_sizes; (void)n_in; (void)out_size; (void)ws_size;
  const int* tokens = (const int*)d_in[0];
  const int* lengths = (const int*)d_in[1];
  const float* Wemb = (const float*)d_in[2];
  const float* Wih_f = (const float*)d_in[3];
  const float* Whh_f = (const float*)d_in[4];
  const float* b_f = (const float*)d_in[5];
  const float* Wih_b = (const float*)d_in[6];
  const float* Whh_b = (const float*)d_in[7];
  const float* b_b = (const float*)d_in[8];
  const float* h0 = (const float*)d_in[9];
  const float* c0 = (const float*)d_in[10];
  const float* Wout = (const float*)d_in[11];
  const float* bout = (const float*)d_in[12];
  const float* trans = (const float*)d_in[13];
  char* ws = (char*)d_ws;
  float* out = (float*)d_out;

  int prep_items = 2 * NT16 * KC_TOT * 64 + 2 * B_ * H_ + S_ * B_ * (KPADX / 8) + 1024;
  hipLaunchKernelGGL(prep_kernel, dim3((prep_items + 255) / 256), dim3(256), 0, stream,
                     Wih_f, Whh_f, Wih_b, Whh_b, h0, tokens, Wemb, ws);
  hipLaunchKernelGGL(lstm_persist, dim3(256), dim3(256), 0, stream, b_f, b_b, c0, ws);
  hipLaunchKernelGGL(feats_kernel, dim3(S_), dim3(256), 0, stream, Wout, bout, ws);
  hipLaunchKernelGGL(crf_kernel, dim3(B_), dim3(64), 0, stream, lengths, trans, ws);
  hipLaunchKernelGGL(final_kernel, dim3(1), dim3(64), 0, stream, ws, out);
}

// Round 4
// 1918.129 us; speedup vs baseline: 10.5122x; 2.1674x over previous
//
#include <hip/hip_runtime.h>
#include <hip/hip_bf16.h>

// ---------------------------------------------------------------------------
// BiLSTM (persistent bf16-MFMA kernel, register-resident weights + cell state,
// BARRIER-FREE data-flow sync: consumers poll sentinel-initialized h slots via
// sc1 relaxed atomics; producers fire-and-forget sc1 stores) + CRF forward.
constexpr int B_ = 64, S_ = 512, E_ = 300, H_ = 512, T_ = 12;
constexpr int G4 = 4 * H_;          // 2048 gate rows
constexpr int KPADX = 320;          // E padded to 320 (zeros 300..319)
constexpr int KTOT = KPADX + H_;    // 832 total K (x | h)
constexpr int KC_TOT = KTOT / 32;   // 26 MFMA k-chunks
constexpr int NT16 = G4 / 16;       // 128 16-wide n tiles
constexpr float NEGV = -10000.0f;
constexpr int ASTR = 840;           // LDS A-row stride in shorts (832 + 8)
constexpr unsigned SENT = 0xFFFFFFFFu;  // sentinel dword (bf16 pair = -NaN,-NaN)

typedef __attribute__((ext_vector_type(8))) short bf16x8_t;
typedef __attribute__((ext_vector_type(4))) float f32x4_t;

// ---- workspace layout (bytes) ---------------------------------------------
constexpr size_t WC_OFF = 0;
constexpr size_t WC_BYTES = (size_t)2 * NT16 * KC_TOT * 64 * 8 * 2;  // 6,815,744
constexpr size_t XC_OFF = WC_OFF + WC_BYTES;
constexpr size_t XC_BYTES = (size_t)S_ * B_ * KPADX * 2;             // 20,971,520
constexpr size_t HH_OFF = XC_OFF + XC_BYTES;
constexpr size_t HH_BYTES = (size_t)2 * (S_ + 1) * B_ * H_ * 2;      // 67,239,936
constexpr size_t FE_OFF = HH_OFF + HH_BYTES;
constexpr size_t FE_BYTES = (size_t)S_ * B_ * T_ * 4;                // 1,572,864
constexpr size_t LSE_OFF = FE_OFF + FE_BYTES;

// ---------------------------------------------------------------------------
// prep: (1) weights -> bf16 MFMA B-fragment order; (2) h0 -> bf16 h_hist slot
// 0; (3) embedding gather xc[s][b][320] bf16; (4) sentinel-fill hh slots 1..S.
__global__ void prep_kernel(const float* __restrict__ Wih_f, const float* __restrict__ Whh_f,
                            const float* __restrict__ Wih_b, const float* __restrict__ Whh_b,
                            const float* __restrict__ h0,
                            const int* __restrict__ tokens, const float* __restrict__ Wemb,
                            char* __restrict__ ws) {
  __hip_bfloat16* wc = (__hip_bfloat16*)(ws + WC_OFF);
  __hip_bfloat16* xc = (__hip_bfloat16*)(ws + XC_OFF);
  __hip_bfloat16* hh = (__hip_bfloat16*)(ws + HH_OFF);
  const int WCN = 2 * NT16 * KC_TOT * 64;   // 425,984
  const int H0N = 2 * B_ * H_;              // 65,536
  const int XCN = S_ * B_ * (KPADX / 8);    // 1,310,720
  const int SFD = (S_ * B_ * H_ * 2) / 16;  // 2,097,152 uint4 per dir
  int idx = blockIdx.x * 256 + threadIdx.x;
  if (idx < WCN) {
    int lane = idx & 63;
    int r = idx >> 6;
    int kc = r % KC_TOT; r /= KC_TOT;
    int tt = r % NT16;
    int dir = r / NT16;
    int n16 = lane & 15, quad = lane >> 4;
    int nt = tt >> 2, gate = tt & 3;
    int j = gate * H_ + nt * 16 + n16;   // original gate row
    int k0 = kc * 32 + quad * 8;
    const float* Wih = dir ? Wih_b : Wih_f;
    const float* Whh = dir ? Whh_b : Whh_f;
    __hip_bfloat16* dst = wc + (size_t)idx * 8;
    #pragma unroll
    for (int jj = 0; jj < 8; jj++) {
      int k = k0 + jj;
      float f;
      if (k < E_) f = Wih[(size_t)j * E_ + k];
      else if (k < KPADX) f = 0.f;
      else f = Whh[(size_t)j * H_ + (k - KPADX)];
      dst[jj] = __float2bfloat16(f);
    }
  } else if (idx < WCN + H0N) {
    int i = idx - WCN;                       // dir*B*H + b*H + h
    int dir = i / (B_ * H_), rem = i % (B_ * H_);
    hh[(size_t)dir * (S_ + 1) * B_ * H_ + rem] = __float2bfloat16(h0[i]);
  } else if (idx < WCN + H0N + XCN) {
    int i = idx - WCN - H0N;                 // sb*40 + c8
    int c8 = i % 40, sb = i / 40;            // sb = s*B + b
    int s = sb >> 6, b = sb & 63;
    int k0 = c8 * 8;
    const float* src = Wemb + (size_t)tokens[(size_t)b * S_ + s] * E_;
    __hip_bfloat16 v[8];
    if (k0 + 8 <= E_) {
      float4 f0 = *(const float4*)(src + k0);
      float4 f1 = *(const float4*)(src + k0 + 4);
      v[0] = __float2bfloat16(f0.x); v[1] = __float2bfloat16(f0.y);
      v[2] = __float2bfloat16(f0.z); v[3] = __float2bfloat16(f0.w);
      v[4] = __float2bfloat16(f1.x); v[5] = __float2bfloat16(f1.y);
      v[6] = __float2bfloat16(f1.z); v[7] = __float2bfloat16(f1.w);
    } else {
      #pragma unroll
      for (int jj = 0; jj < 8; jj++) {
        int k = k0 + jj;
        v[jj] = __float2bfloat16(k < E_ ? src[k] : 0.f);
      }
    }
    *(uint4*)(xc + (size_t)sb * KPADX + k0) = *(const uint4*)v;
  } else if (idx < WCN + H0N + XCN + 2 * SFD) {
    int i = idx - WCN - H0N - XCN;
    int dir = i / SFD, j = i % SFD;
    // sentinel-fill hh[dir][1..S][*][*]
    uint4* dst = (uint4*)(hh + (size_t)dir * (S_ + 1) * B_ * H_ + B_ * H_);
    uint4 sv; sv.x = SENT; sv.y = SENT; sv.z = SENT; sv.w = SENT;
    dst[j] = sv;
  }
}

// ---------------------------------------------------------------------------
// Persistent BiLSTM. grid = 256 = dir(2) x nt(32) x mt(4), block = 256.
// Weights in registers; cell state in a register. NO barrier: consumers poll
// h(s) dwords (sentinel-initialized) with sc1 relaxed loads; producers store
// h(s+1) with sc1 relaxed dword stores and continue immediately.
__launch_bounds__(256, 1)
__global__ void lstm_persist(const float* __restrict__ bias_f,
                             const float* __restrict__ bias_b,
                             const float* __restrict__ c0,
                             char* __restrict__ ws) {
  __shared__ short pool[16 * ASTR];      // 26,880 B A-tile
  __shared__ float gl[4 * 16 * 17];      // 4,352 B gate exchange
  const int bid = blockIdx.x;
  const int dir = bid >> 7, rr_ = bid & 127, nt = rr_ >> 2, mt = rr_ & 3;
  const int tid = threadIdx.x, lane = tid & 63, wv = tid >> 6;
  const int quad = lane >> 4, l16 = lane & 15;
  const __hip_bfloat16* wc = (const __hip_bfloat16*)(ws + WC_OFF);
  const __hip_bfloat16* xc = (const __hip_bfloat16*)(ws + XC_OFF);
  unsigned* hh_u = (unsigned*)(ws + HH_OFF);
  unsigned long long* hh_q = (unsigned long long*)(ws + HH_OFF);

  // --- load B fragments into registers, once ---
  bf16x8_t bfr[KC_TOT];
  #pragma unroll
  for (int kc = 0; kc < KC_TOT; kc++) {
    size_t boff = (((size_t)dir * NT16 + (nt * 4 + wv)) * KC_TOT + kc) * 64 + lane;
    bfr[kc] = *(const bf16x8_t*)(wc + boff * 8);
  }
  // --- per-thread cell state + biases ---
  const int bo = tid >> 4, hl = tid & 15;       // batch-offset, h-offset
  const int b = mt * 16 + bo, hg = nt * 16 + hl;
  float c = c0[(size_t)(dir * B_ + b) * H_ + hg];
  const float* bias = dir ? bias_b : bias_f;
  const float bi_i = bias[0 * H_ + hg], bi_f = bias[1 * H_ + hg];
  const float bi_g = bias[2 * H_ + hg], bi_o = bias[3 * H_ + hg];

  // --- pre-stage x(0) into pool x-region (cached loads; xc never stale) ---
  {
    int spos0 = dir ? (S_ - 1) : 0;
    for (int i = tid; i < 16 * 40; i += 256) {
      int row = i / 40, c8 = i % 40;
      *(uint4*)(pool + row * ASTR + c8 * 8) =
          *(const uint4*)(xc + ((size_t)spos0 * B_ + mt * 16 + row) * KPADX + c8 * 8);
    }
  }

  // poll-address map: k=0..7, i = tid + k*256, row = i>>7 (batch-offset),
  // c2 = i&127 (8B column) -> coalesced 512B per wave, LDS b64 conflict-free.
  for (int s = 0; s < S_; s++) {
    // --- poll + load h(s): sc1 loads until no dword is sentinel ---
    const size_t qbase = ((size_t)(dir * (S_ + 1) + s) * B_ + mt * 16) * (H_ / 4);
    unsigned long long hv[8];
    bool ok = false;
    while (!ok) {
      ok = true;
      #pragma unroll
      for (int k = 0; k < 8; k++) {
        int i = tid + k * 256;
        int row = i >> 7, c2 = i & 127;
        hv[k] = __hip_atomic_load(&hh_q[qbase + (size_t)row * (H_ / 4) + c2],
                                  __ATOMIC_RELAXED, __HIP_MEMORY_SCOPE_AGENT);
        ok = ok && ((unsigned)hv[k] != SENT) && ((unsigned)(hv[k] >> 32) != SENT);
      }
      if (!ok) __builtin_amdgcn_s_sleep(1);
    }
    #pragma unroll
    for (int k = 0; k < 8; k++) {
      int i = tid + k * 256;
      int row = i >> 7, c2 = i & 127;
      *(unsigned long long*)(pool + row * ASTR + KPADX + c2 * 4) = hv[k];
    }
    __syncthreads();
    // --- MFMA K-loop: 26 chunks, B from registers ---
    f32x4_t acc = (f32x4_t)(0.f);
    #pragma unroll
    for (int kc = 0; kc < KC_TOT; kc++) {
      bf16x8_t af = *(const bf16x8_t*)(pool + l16 * ASTR + kc * 32 + quad * 8);
      acc = __builtin_amdgcn_mfma_f32_16x16x32_bf16(af, bfr[kc], acc, 0, 0, 0);
    }
    __syncthreads();   // pool A-reads done
    // --- gate exchange: C/D row = quad*4+r = batch-offset, col = l16 = hl ---
    #pragma unroll
    for (int r = 0; r < 4; r++)
      gl[(wv * 16 + quad * 4 + r) * 17 + l16] = acc[r];
    // --- overlap: prefetch x(s+1) into pool x-region (h-independent) ---
    if (s + 1 < S_) {
      int sposn = dir ? (S_ - 2 - s) : (s + 1);
      for (int i = tid; i < 16 * 40; i += 256) {
        int row = i / 40, c8 = i % 40;
        *(uint4*)(pool + row * ASTR + c8 * 8) =
            *(const uint4*)(xc + ((size_t)sposn * B_ + mt * 16 + row) * KPADX + c8 * 8);
      }
    }
    __syncthreads();
    // --- elementwise cell update (c in register) ---
    float gi = gl[(0 * 16 + bo) * 17 + hl] + bi_i;
    float gf = gl[(1 * 16 + bo) * 17 + hl] + bi_f;
    float gg = gl[(2 * 16 + bo) * 17 + hl] + bi_g;
    float go = gl[(3 * 16 + bo) * 17 + hl] + bi_o;
    float ii = 1.f / (1.f + __expf(-gi));
    float ff = 1.f / (1.f + __expf(-gf));
    float gt = 1.f - 2.f / (1.f + __expf(2.f * gg));   // tanh
    float oo = 1.f / (1.f + __expf(-go));
    c = ff * c + ii * gt;
    float hv2 = oo * (1.f - 2.f / (1.f + __expf(2.f * c)));
    // --- h store: pack 2 bf16 -> one sc1 dword store; fire-and-forget ---
    float hn = __shfl_xor(hv2, 1, 64);    // partner shares (bo, hl^1)
    if ((hl & 1) == 0) {
      unsigned short ulo = __builtin_bit_cast(unsigned short, __float2bfloat16(hv2));
      unsigned short uhi = __builtin_bit_cast(unsigned short, __float2bfloat16(hn));
      unsigned pk = ((unsigned)uhi << 16) | (unsigned)ulo;
      size_t uidx = (((size_t)(dir * (S_ + 1) + s + 1) * B_ + b) * H_ + hg) >> 1;
      __hip_atomic_store(hh_u + uidx, pk, __ATOMIC_RELAXED, __HIP_MEMORY_SCOPE_AGENT);
    }
    // no barrier — next iteration's data-poll is the synchronization
  }
}

// ---------------------------------------------------------------------------
// feats[(b*S+s)*T + t] = [hf(s) | hb(s)] . W_out[t,:] + b_out[t]. block per s.
// Output layout [b][s][t] so the CRF scan reads contiguously per batch.
__launch_bounds__(256)
__global__ void feats_kernel(const float* __restrict__ Wout,
                             const float* __restrict__ bout,
                             char* __restrict__ ws) {
  __shared__ float wl[12 * 1024];   // 48 KB
  const int s = blockIdx.x, tid = threadIdx.x;
  for (int i = tid; i < 12 * 1024 / 4; i += 256)
    *(float4*)(wl + i * 4) = *(const float4*)(Wout + i * 4);
  __syncthreads();
  const __hip_bfloat16* hh = (const __hip_bfloat16*)(ws + HH_OFF);
  float* fe = (float*)(ws + FE_OFF);
  int b = tid >> 2, tg = tid & 3, t0 = tg * 3;
  const __hip_bfloat16* hf = hh + (size_t)(0 * (S_ + 1) + s + 1) * B_ * H_ + (size_t)b * H_;
  const __hip_bfloat16* hb = hh + (size_t)(1 * (S_ + 1) + (S_ - s)) * B_ * H_ + (size_t)b * H_;
  float a0 = 0.f, a1 = 0.f, a2 = 0.f;
  for (int half = 0; half < 2; half++) {
    const __hip_bfloat16* hp = half ? hb : hf;
    int wof = half * 512;
    for (int k = 0; k < 512; k += 8) {
      uint4 raw = *(const uint4*)(hp + k);
      const __hip_bfloat16* hv = (const __hip_bfloat16*)&raw;
      float hfl[8];
      #pragma unroll
      for (int j = 0; j < 8; j++) hfl[j] = __bfloat162float(hv[j]);
      #pragma unroll
      for (int j = 0; j < 8; j++) {
        a0 += hfl[j] * wl[(t0 + 0) * 1024 + wof + k + j];
        a1 += hfl[j] * wl[(t0 + 1) * 1024 + wof + k + j];
        a2 += hfl[j] * wl[(t0 + 2) * 1024 + wof + k + j];
      }
    }
  }
  float* o = fe + ((size_t)b * S_ + s) * T_;
  o[t0 + 0] = a0 + bout[t0 + 0];
  o[t0 + 1] = a1 + bout[t0 + 1];
  o[t0 + 2] = a2 + bout[t0 + 2];
}

// ---------------------------------------------------------------------------
// CRF forward scan: one wave per batch element; lane = next-tag (<12).
// Software-pipelined: load feat(s+1) while computing step s.
__launch_bounds__(64)
__global__ void crf_kernel(const int* __restrict__ lengths,
                           const float* __restrict__ trans,
                           char* __restrict__ ws) {
  const int b = blockIdx.x, lane = threadIdx.x;
  const float* fe = (const float*)(ws + FE_OFF);
  float* lse = (float*)(ws + LSE_OFF);
  const float* fb = fe + (size_t)b * S_ * T_;
  float tr[12];
  #pragma unroll
  for (int p = 0; p < 12; p++) tr[p] = (lane < 12) ? trans[lane * 12 + p] : 0.f;
  float tstop = (lane < 12) ? trans[11 * 12 + lane] : 0.f;  // STOP row
  float alpha = (lane == 10) ? 0.f : NEGV;                  // START tag
  const int len = lengths[b];
  float feat = (lane < 12) ? fb[lane] : 0.f;
  for (int s = 0; s < S_; s++) {
    float fn = (lane < 12 && s + 1 < S_) ? fb[(size_t)(s + 1) * T_ + lane] : 0.f;
    float av[12];
    #pragma unroll
    for (int p = 0; p < 12; p++) av[p] = __shfl(alpha, p, 64) + tr[p];
    float mx = av[0];
    #pragma unroll
    for (int p = 1; p < 12; p++) mx = fmaxf(mx, av[p]);
    float sum = 0.f;
    #pragma unroll
    for (int p = 0; p < 12; p++) sum += __expf(av[p] - mx);
    float nw = mx + __logf(sum) + feat;
    if (s < len && lane < 12) alpha = nw;
    feat = fn;
  }
  float tv = (lane < 12) ? (alpha + tstop) : -3.0e38f;
  float mx = tv;
  #pragma unroll
  for (int off = 32; off > 0; off >>= 1) mx = fmaxf(mx, __shfl_xor(mx, off, 64));
  float sum = __expf(tv - mx);
  #pragma unroll
  for (int off = 32; off > 0; off >>= 1) sum += __shfl_xor(sum, off, 64);
  if (lane == 0) lse[b] = mx + __logf(sum);
}

__global__ void final_kernel(char* __restrict__ ws, float* __restrict__ out) {
  const float* lse = (const float*)(ws + LSE_OFF);
  float v = lse[threadIdx.x];
  #pragma unroll
  for (int off = 32; off > 0; off >>= 1) v += __shfl_xor(v, off, 64);
  if (threadIdx.x == 0) out[0] = v * (1.f / 64.f);
}

// ---------------------------------------------------------------------------
extern "C" void kernel_launch(void* const* d_in, const int* in_sizes, int n_in,
                              void* d_out, int out_size, void* d_ws, size_t ws_size,
                              hipStream_t stream) {
  (void)in_sizes; (void)n_in; (void)out_size; (void)ws_size;
  const int* tokens = (const int*)d_in[0];
  const int* lengths = (const int*)d_in[1];
  const float* Wemb = (const float*)d_in[2];
  const float* Wih_f = (const float*)d_in[3];
  const float* Whh_f = (const float*)d_in[4];
  const float* b_f = (const float*)d_in[5];
  const float* Wih_b = (const float*)d_in[6];
  const float* Whh_b = (const float*)d_in[7];
  const float* b_b = (const float*)d_in[8];
  const float* h0 = (const float*)d_in[9];
  const float* c0 = (const float*)d_in[10];
  const float* Wout = (const float*)d_in[11];
  const float* bout = (const float*)d_in[12];
  const float* trans = (const float*)d_in[13];
  char* ws = (char*)d_ws;
  float* out = (float*)d_out;

  int prep_items = 2 * NT16 * KC_TOT * 64 + 2 * B_ * H_ + S_ * B_ * (KPADX / 8)
                 + 2 * (S_ * B_ * H_ * 2) / 16;
  hipLaunchKernelGGL(prep_kernel, dim3((prep_items + 255) / 256), dim3(256), 0, stream,
                     Wih_f, Whh_f, Wih_b, Whh_b, h0, tokens, Wemb, ws);
  hipLaunchKernelGGL(lstm_persist, dim3(256), dim3(256), 0, stream, b_f, b_b, c0, ws);
  hipLaunchKernelGGL(feats_kernel, dim3(S_), dim3(256), 0, stream, Wout, bout, ws);
  hipLaunchKernelGGL(crf_kernel, dim3(B_), dim3(64), 0, stream, lengths, trans, ws);
  hipLaunchKernelGGL(final_kernel, dim3(1), dim3(64), 0, stream, ws, out);
}